// Round 1
// 332.369 us; speedup vs baseline: 1.1377x; 1.1377x over previous
//
#include <hip/hip_runtime.h>
#include <math.h>

namespace {
constexpr int BB = 32, NPG = 4096, NTOT = BB*NPG, C = 128, FIN = 64, KK = 32, JJ = 40;
constexpr int YROWS = BB*JJ; // 1280
constexpr float EPS = 1e-5f;

// CW (precomputed folded constants) float offsets
constexpr int CW_WU  = 0;      // [64][32] Wu[d][k] = sum_c W[c][d]*U[c][k]
constexpr int CW_WV  = 2048;   // [64][32] Wv[d][k] = sum_c W[c][d]*V[c][k]
constexpr int CW_VU  = 4096;   // [32][32] VU[k'][k] = sum_c V[c][k']*U[c][k]
constexpr int CW_WG  = 5120;   // [64]     sum_c W[c][d]*gw[c]
constexpr int CW_VGX = 5184;   // [32]     sum_c V[c][k]*gw[c]
constexpr int CW_VGH = 5216;   // [32]     sum_c V[c][k]*gw[128+c]
constexpr int CW_CBU = 5248;   // [32]     sum_c b[c]*U[c][k]
constexpr int CW_CSU = 5280;   // [32]     sum_c U[c][k]
constexpr int CW_CBV = 5312;   // [32]     sum_c b[c]*V[c][k]
constexpr int CW_CSV = 5344;   // [32]     sum_c V[c][k]
constexpr int CW_SC  = 5376;   // bG = b.gw[0:128], sG = sum gw[0:128]
constexpr int CW_SIZE = 5384;

// workspace layout (float offsets), all fp32 except ST (double)
constexpr size_t XU_OFF  = 0;                               // NTOT*32
constexpr size_t GX_OFF  = XU_OFF + (size_t)NTOT*KK;        // NTOT
constexpr size_t YP_OFF  = GX_OFF + (size_t)NTOT;           // 1280*32
constexpr size_t PMA_OFF = YP_OFF + (size_t)YROWS*KK;       // 32*40*64
constexpr size_t PSA_OFF = PMA_OFF + 81920;
constexpr size_t PMB_OFF = PSA_OFF + 81920;
constexpr size_t PSB_OFF = PMB_OFF + 81920;
constexpr size_t CWS_OFF = PSB_OFF + 81920;
constexpr size_t ST_OFF  = CWS_OFF + CW_SIZE;               // 4 doubles (even float offset)
}

#define ACC8(A, wv, u0, u1) do { \
  A[0] += (wv)*(u0).x; A[1] += (wv)*(u0).y; A[2] += (wv)*(u0).z; A[3] += (wv)*(u0).w; \
  A[4] += (wv)*(u1).x; A[5] += (wv)*(u1).y; A[6] += (wv)*(u1).z; A[7] += (wv)*(u1).w; } while(0)

// ---------------------------------------------------------------------------
// K0: fold W/U/V/gate into small matrices. One block.
// ---------------------------------------------------------------------------
__global__ __launch_bounds__(256)
void k_pre(const float* __restrict__ W, const float* __restrict__ b,
           const float* __restrict__ U, const float* __restrict__ V,
           const float* __restrict__ gw, float* __restrict__ CWo) {
  __shared__ float W_l[128*64];
  __shared__ float V_l[128*32];
  const int t = threadIdx.x;
  for (int f = t; f < 2048; f += 256) *(float4*)(W_l + 4*f) = *(const float4*)(W + 4*f);
  for (int f = t; f < 1024; f += 256) *(float4*)(V_l + 4*f) = *(const float4*)(V + 4*f);
  __syncthreads();
  {
    const int d = t >> 2, k0 = (t & 3) * 8;
    float au[8] = {0,0,0,0,0,0,0,0};
    float av[8] = {0,0,0,0,0,0,0,0};
    for (int c = 0; c < 128; ++c) {
      const float wv = W_l[c*64 + d];
      const float4 u0 = *(const float4*)(U + c*32 + k0);
      const float4 u1 = *(const float4*)(U + c*32 + k0 + 4);
      ACC8(au, wv, u0, u1);
      const float4 v0 = *(const float4*)(V_l + c*32 + k0);
      const float4 v1 = *(const float4*)(V_l + c*32 + k0 + 4);
      ACC8(av, wv, v0, v1);
    }
    *(float4*)(CWo + CW_WU + d*32 + k0)     = make_float4(au[0],au[1],au[2],au[3]);
    *(float4*)(CWo + CW_WU + d*32 + k0 + 4) = make_float4(au[4],au[5],au[6],au[7]);
    *(float4*)(CWo + CW_WV + d*32 + k0)     = make_float4(av[0],av[1],av[2],av[3]);
    *(float4*)(CWo + CW_WV + d*32 + k0 + 4) = make_float4(av[4],av[5],av[6],av[7]);
  }
  if (t < 128) {
    const int kp = t >> 2, k0 = (t & 3) * 8;
    float a[8] = {0,0,0,0,0,0,0,0};
    for (int c = 0; c < 128; ++c) {
      const float vv = V_l[c*32 + kp];
      const float4 u0 = *(const float4*)(U + c*32 + k0);
      const float4 u1 = *(const float4*)(U + c*32 + k0 + 4);
      ACC8(a, vv, u0, u1);
    }
    *(float4*)(CWo + CW_VU + kp*32 + k0)     = make_float4(a[0],a[1],a[2],a[3]);
    *(float4*)(CWo + CW_VU + kp*32 + k0 + 4) = make_float4(a[4],a[5],a[6],a[7]);
  }
  if (t < 64) {
    float a = 0.f;
    for (int c = 0; c < 128; ++c) a += W_l[c*64 + t] * gw[c];
    CWo[CW_WG + t] = a;
  }
  if (t < 32) {
    float a1=0,a2=0,a3=0,a4=0,a5=0,a6=0;
    for (int c = 0; c < 128; ++c) {
      const float uv = U[c*32 + t], vv = V_l[c*32 + t], bc = b[c];
      a1 += vv*gw[c]; a2 += vv*gw[128+c];
      a3 += bc*uv;    a4 += uv;
      a5 += bc*vv;    a6 += vv;
    }
    CWo[CW_VGX+t]=a1; CWo[CW_VGH+t]=a2; CWo[CW_CBU+t]=a3; CWo[CW_CSU+t]=a4;
    CWo[CW_CBV+t]=a5; CWo[CW_CSV+t]=a6;
  }
  if (t == 0) {
    float bg=0.f, sg=0.f;
    for (int c = 0; c < 128; ++c) { bg += b[c]*gw[c]; sg += gw[c]; }
    CWo[CW_SC+0]=bg; CWo[CW_SC+1]=sg;
  }
}

// ---------------------------------------------------------------------------
// K1: stats-only pass: sum/sumsq of in@W^T + b (double), no store of X.
// ---------------------------------------------------------------------------
__global__ __launch_bounds__(256,3)
void k_stat(const float* __restrict__ inp, const float* __restrict__ W,
            const float* __restrict__ bias, double* __restrict__ stats) {
  __shared__ float in_t[64*64];
  __shared__ float w_l[128*64];
  __shared__ double dred[8];
  const int t = threadIdx.x;
  const int r0 = blockIdx.x * 64;
  #pragma unroll
  for (int s = 0; s < 4; ++s) {
    int f = (t + 256*s) * 4;
    int r = f >> 6, d = f & 63;
    float4 v = *(const float4*)(inp + (size_t)r0*FIN + f);
    *(float4*)(in_t + r*64 + (d ^ ((r & 7) * 8))) = v;
  }
  #pragma unroll
  for (int s = 0; s < 8; ++s) {
    int f = (t + 256*s) * 4;
    int r = f >> 6, d = f & 63;
    float4 w = *(const float4*)(W + f);
    *(float4*)(w_l + r*64 + (d ^ ((r & 7) * 8))) = w;
  }
  __syncthreads();
  const int rg = t >> 4;
  const int cg = t & 15;
  const int swi = (rg & 7) * 8;
  const int sww = (cg & 7) * 8;
  float acc[4][8];
  #pragma unroll
  for (int i=0;i<4;i++)
    #pragma unroll
    for (int j=0;j<8;j++) acc[i][j] = 0.f;
  #pragma unroll
  for (int dc = 0; dc < 16; ++dc) {
    const int d = dc*4;
    const int di = d ^ swi, dw = d ^ sww;
    float4 a[4], w4[8];
    #pragma unroll
    for (int i=0;i<4;i++) a[i]  = *(const float4*)(in_t + (rg+16*i)*64 + di);
    #pragma unroll
    for (int j=0;j<8;j++) w4[j] = *(const float4*)(w_l  + (cg+16*j)*64 + dw);
    #pragma unroll
    for (int i=0;i<4;i++)
      #pragma unroll
      for (int j=0;j<8;j++)
        acc[i][j] += a[i].x*w4[j].x + a[i].y*w4[j].y + a[i].z*w4[j].z + a[i].w*w4[j].w;
  }
  double ds = 0.0, dss = 0.0;
  #pragma unroll
  for (int i=0;i<4;i++) {
    #pragma unroll
    for (int j=0;j<8;j++) {
      const int c = cg + 16*j;
      float v = acc[i][j] + bias[c];
      ds += (double)v; dss += (double)v*(double)v;
    }
  }
  #pragma unroll
  for (int off = 32; off > 0; off >>= 1) {
    ds  += __shfl_down(ds, off);
    dss += __shfl_down(dss, off);
  }
  if ((t & 63) == 0) { dred[(t>>6)*2] = ds; dred[(t>>6)*2+1] = dss; }
  __syncthreads();
  if (t == 0) {
    atomicAdd(stats+0, dred[0]+dred[2]+dred[4]+dred[6]);
    atomicAdd(stats+1, dred[1]+dred[3]+dred[5]+dred[7]);
  }
}

// ---------------------------------------------------------------------------
// Shared device helpers: I-row compute (per-lane 8 ks, 4-lane groups) and
// softmax-partials output (max + sumexp per (b,j), 64-wide blocks).
// ---------------------------------------------------------------------------
__device__ __forceinline__ void irow_compute(const float* ypj, const float xp[8],
                                             const int kq, float4 p[10]) {
  #pragma unroll
  for (int m = 0; m < 10; ++m) {
    float4 acc;
    #pragma unroll
    for (int jj = 0; jj < 4; ++jj) {
      const int j = 4*m + jj;
      const float4 y0 = *(const float4*)(ypj + j*32 + kq*8);
      const float4 y1 = *(const float4*)(ypj + j*32 + kq*8 + 4);
      const float s = xp[0]*y0.x + xp[1]*y0.y + xp[2]*y0.z + xp[3]*y0.w
                    + xp[4]*y1.x + xp[5]*y1.y + xp[6]*y1.z + xp[7]*y1.w;
      if (jj==0) acc.x = s; else if (jj==1) acc.y = s; else if (jj==2) acc.z = s; else acc.w = s;
    }
    acc.x += __shfl_xor(acc.x,1); acc.x += __shfl_xor(acc.x,2);
    acc.y += __shfl_xor(acc.y,1); acc.y += __shfl_xor(acc.y,2);
    acc.z += __shfl_xor(acc.z,1); acc.z += __shfl_xor(acc.z,2);
    acc.w += __shfl_xor(acc.w,1); acc.w += __shfl_xor(acc.w,2);
    p[m] = acc;
  }
}

__device__ __forceinline__ void partials_out(const float4 p[10], const int t, const int kq,
    float* sredm, float* sreds, float* redm,
    float* __restrict__ PmB, float* __restrict__ PsB) {
  float ev[10];
  #pragma unroll
  for (int m = 0; m < 10; ++m) {
    const float4 qv = p[m];
    ev[m] = (kq&1) ? ((kq&2)? qv.w : qv.y) : ((kq&2)? qv.z : qv.x);
  }
  const int w = t >> 6, tl = t & 63;
  float mv[10];
  #pragma unroll
  for (int m = 0; m < 10; ++m) {
    mv[m] = ev[m];
    mv[m] = fmaxf(mv[m], __shfl_xor(mv[m], 4));
    mv[m] = fmaxf(mv[m], __shfl_xor(mv[m], 8));
    mv[m] = fmaxf(mv[m], __shfl_xor(mv[m], 16));
    mv[m] = fmaxf(mv[m], __shfl_xor(mv[m], 32));
  }
  if (tl < 4) {
    #pragma unroll
    for (int m = 0; m < 10; ++m) sredm[w*40 + 4*m + kq] = mv[m];
  }
  __syncthreads();
  if (t < 40)
    redm[t] = fmaxf(fmaxf(sredm[t], sredm[40+t]), fmaxf(sredm[80+t], sredm[120+t]));
  __syncthreads();
  float es[10];
  #pragma unroll
  for (int m = 0; m < 10; ++m) {
    const float M = redm[4*m + kq];
    es[m] = __expf(ev[m]-M);
    es[m] += __shfl_xor(es[m], 4);
    es[m] += __shfl_xor(es[m], 8);
    es[m] += __shfl_xor(es[m], 16);
    es[m] += __shfl_xor(es[m], 32);
  }
  if (tl < 4) {
    #pragma unroll
    for (int m = 0; m < 10; ++m) sreds[w*40 + 4*m + kq] = es[m];
  }
  __syncthreads();
  if (t < 40) {
    PmB[(size_t)t*64] = redm[t];
    PsB[(size_t)t*64] = sreds[t]+sreds[40+t]+sreds[80+t]+sreds[120+t];
  }
}

// ---------------------------------------------------------------------------
// K2: y_p directly from fe: yp = relu(q*relu(ry*(fe@Wv + cbV) - ry*my*csV)).
// ---------------------------------------------------------------------------
__global__ __launch_bounds__(256,4)
void k_yp2(const float* __restrict__ fe, const float* __restrict__ CW,
           const float* __restrict__ q, const double* __restrict__ ST,
           float* __restrict__ yp) {
  __shared__ float in_t[64*64];
  __shared__ float Wl[64*32];
  const int t = threadIdx.x;
  const int r0 = blockIdx.x * 64;
  #pragma unroll
  for (int s = 0; s < 4; ++s) {
    int f = (t + 256*s) * 4;
    int r = f >> 6, d = f & 63;
    float4 v = *(const float4*)(fe + (size_t)r0*FIN + f);
    *(float4*)(in_t + r*64 + (d ^ ((r & 7) * 8))) = v;
  }
  #pragma unroll
  for (int s = 0; s < 2; ++s) {
    int f = (t + 256*s) * 4;
    *(float4*)(Wl + f) = *(const float4*)(CW + CW_WV + f);
  }
  __syncthreads();
  const double cy = (double)YROWS * (double)C;
  const double myd = ST[2]/cy, vy = ST[3]/cy - myd*myd;
  const float ry = (float)(1.0/sqrt(vy + (double)EPS));
  const float mr = (float)myd * ry;
  const int r2 = t >> 2, kq = t & 3;
  const int swz = (r2 & 7) * 8;
  float acc[8] = {0,0,0,0,0,0,0,0};
  #pragma unroll
  for (int dc = 0; dc < 16; ++dc) {
    const int d = dc*4;
    const float4 a = *(const float4*)(in_t + r2*64 + (d ^ swz));
    { const float4 w0 = *(const float4*)(Wl + (d+0)*32 + kq*8);
      const float4 w1 = *(const float4*)(Wl + (d+0)*32 + kq*8 + 4); ACC8(acc, a.x, w0, w1); }
    { const float4 w0 = *(const float4*)(Wl + (d+1)*32 + kq*8);
      const float4 w1 = *(const float4*)(Wl + (d+1)*32 + kq*8 + 4); ACC8(acc, a.y, w0, w1); }
    { const float4 w0 = *(const float4*)(Wl + (d+2)*32 + kq*8);
      const float4 w1 = *(const float4*)(Wl + (d+2)*32 + kq*8 + 4); ACC8(acc, a.z, w0, w1); }
    { const float4 w0 = *(const float4*)(Wl + (d+3)*32 + kq*8);
      const float4 w1 = *(const float4*)(Wl + (d+3)*32 + kq*8 + 4); ACC8(acc, a.w, w0, w1); }
  }
  #pragma unroll
  for (int i = 0; i < 8; ++i) {
    const int k = kq*8 + i;
    const float typ = ry*(acc[i] + CW[CW_CBV+k]) - mr*CW[CW_CSV+k];
    float v = fmaxf(typ, 0.f);
    acc[i] = fmaxf(q[k]*v, 0.f);
  }
  *(float4*)(yp + (size_t)(r0+r2)*KK + kq*8)     = make_float4(acc[0],acc[1],acc[2],acc[3]);
  *(float4*)(yp + (size_t)(r0+r2)*KK + kq*8 + 4) = make_float4(acc[4],acc[5],acc[6],acc[7]);
}

// ---------------------------------------------------------------------------
// K3: layer-0: xu = rx*(nf@Wu + cbU) - rx*mx*csU (normalized x@U), gx scalar,
// x_p = relu(xu), I row, softmax partials (64-wide). No X, no Ibf.
// ---------------------------------------------------------------------------
__global__ __launch_bounds__(256,4)
void k_I0(const float* __restrict__ nf, const float* __restrict__ CW,
          const double* __restrict__ ST, const float* __restrict__ yp,
          float* __restrict__ XU, float* __restrict__ GX,
          float* __restrict__ Pm, float* __restrict__ Ps) {
  __shared__ float in_t[64*64];
  __shared__ float Wl[64*32];
  __shared__ float ypj[40*32];
  __shared__ float wgl[64];
  __shared__ float sredm[160], sreds[160], redm[40];
  const int t = threadIdx.x;
  const int bid = blockIdx.x;
  const int b = bid >> 6, blk = bid & 63;
  const size_t rowbase = (size_t)b*NPG + (size_t)blk*64;
  #pragma unroll
  for (int s = 0; s < 4; ++s) {
    int f = (t + 256*s) * 4;
    int r = f >> 6, d = f & 63;
    float4 v = *(const float4*)(nf + rowbase*FIN + f);
    *(float4*)(in_t + r*64 + (d ^ ((r & 7) * 8))) = v;
  }
  #pragma unroll
  for (int s = 0; s < 2; ++s) {
    int f = (t + 256*s) * 4;
    *(float4*)(Wl + f) = *(const float4*)(CW + CW_WU + f);
  }
  for (int f4v = t; f4v < 320; f4v += 256)
    *(float4*)(ypj + f4v*4) = *(const float4*)(yp + (size_t)b*(JJ*KK) + f4v*4);
  if (t < 64) wgl[t] = CW[CW_WG + t];
  __syncthreads();
  const double cx = (double)NTOT * (double)C;
  const double mx = ST[0]/cx, vx = ST[1]/cx - mx*mx;
  const float rx = (float)(1.0/sqrt(vx + (double)EPS));
  const float mr = (float)mx * rx;
  const int r2 = t >> 2, kq = t & 3;
  const int swz = (r2 & 7) * 8;
  float acc[8] = {0,0,0,0,0,0,0,0};
  #pragma unroll
  for (int dc = 0; dc < 16; ++dc) {
    const int d = dc*4;
    const float4 a = *(const float4*)(in_t + r2*64 + (d ^ swz));
    { const float4 w0 = *(const float4*)(Wl + (d+0)*32 + kq*8);
      const float4 w1 = *(const float4*)(Wl + (d+0)*32 + kq*8 + 4); ACC8(acc, a.x, w0, w1); }
    { const float4 w0 = *(const float4*)(Wl + (d+1)*32 + kq*8);
      const float4 w1 = *(const float4*)(Wl + (d+1)*32 + kq*8 + 4); ACC8(acc, a.y, w0, w1); }
    { const float4 w0 = *(const float4*)(Wl + (d+2)*32 + kq*8);
      const float4 w1 = *(const float4*)(Wl + (d+2)*32 + kq*8 + 4); ACC8(acc, a.z, w0, w1); }
    { const float4 w0 = *(const float4*)(Wl + (d+3)*32 + kq*8);
      const float4 w1 = *(const float4*)(Wl + (d+3)*32 + kq*8 + 4); ACC8(acc, a.w, w0, w1); }
  }
  // gx partial over this lane's d-range, reduce over group
  float gp = 0.f;
  #pragma unroll
  for (int u = 0; u < 4; ++u) {
    const int d = kq*16 + 4*u;
    const float4 a = *(const float4*)(in_t + r2*64 + (d ^ swz));
    const float4 w = *(const float4*)(wgl + d);
    gp += a.x*w.x + a.y*w.y + a.z*w.z + a.w*w.w;
  }
  gp += __shfl_xor(gp, 1); gp += __shfl_xor(gp, 2);
  float xp[8];
  #pragma unroll
  for (int i = 0; i < 8; ++i) {
    const int k = kq*8 + i;
    const float xv = rx*(acc[i] + CW[CW_CBU+k]) - mr*CW[CW_CSU+k];
    acc[i] = xv;
    xp[i] = fmaxf(xv, 0.f);
  }
  *(float4*)(XU + (rowbase+r2)*KK + kq*8)     = make_float4(acc[0],acc[1],acc[2],acc[3]);
  *(float4*)(XU + (rowbase+r2)*KK + kq*8 + 4) = make_float4(acc[4],acc[5],acc[6],acc[7]);
  if (kq == 0) GX[rowbase + r2] = rx*(gp + CW[CW_SC+0]) - mr*CW[CW_SC+1];
  float4 p[10];
  irow_compute(ypj, xp, kq, p);
  partials_out(p, t, kq, sredm, sreds, redm,
               Pm + (size_t)b*2560 + blk, Ps + (size_t)b*2560 + blk);
}

// ---------------------------------------------------------------------------
// K4: fused layer update in K-space only:
// recompute I from xu -> A -> h = A@yp -> hu = h@VU, gate via vgx/vgh ->
// blend xu/gx -> new I -> partials (or FINAL: out = sigmoid(sum_j I^2)).
// ---------------------------------------------------------------------------
template<int FINAL>
__global__ __launch_bounds__(256,4)
void k_fused2(float* __restrict__ XU, float* __restrict__ GX,
              const float* __restrict__ yp, const float* __restrict__ CW,
              const float* __restrict__ gb,
              const float* __restrict__ PmIn, const float* __restrict__ PsIn,
              float* __restrict__ PmOut, float* __restrict__ PsOut,
              float* __restrict__ outp) {
  __shared__ float ypj[40*32];
  __shared__ float e_l[64*44];
  __shared__ float h_l[64*40];
  __shared__ float VUl[32*32];
  __shared__ float M_l[40], Si_l[40];
  __shared__ float vgxl[32], vghl[32];
  float* sredm = e_l;          // overlay: e_l dead by partials time
  float* sreds = e_l + 160;
  float* redm  = e_l + 320;
  const int t = threadIdx.x;
  const int bid = blockIdx.x;
  const int b = bid >> 6, blk = bid & 63;
  const size_t rowbase = (size_t)b*NPG + (size_t)blk*64;
  if (t < 40) {
    const float* pm = PmIn + ((size_t)b*40 + t)*64;
    const float* ps = PsIn + ((size_t)b*40 + t)*64;
    float M = 0.f;
    for (int k2 = 0; k2 < 64; ++k2) M = fmaxf(M, pm[k2]);
    float S = 0.f;
    for (int k2 = 0; k2 < 64; ++k2) S += ps[k2]*__expf(pm[k2]-M);
    M_l[t] = M; Si_l[t] = 1.f/S;
  }
  for (int f4v = t; f4v < 320; f4v += 256)
    *(float4*)(ypj + f4v*4) = *(const float4*)(yp + (size_t)b*(JJ*KK) + f4v*4);
  { const int f = t*4;
    *(float4*)(VUl + f) = *(const float4*)(CW + CW_VU + f); }
  if (t < 32) { vgxl[t] = CW[CW_VGX+t]; vghl[t] = CW[CW_VGH+t]; }
  __syncthreads();
  const int r2 = t >> 2, kq = t & 3;
  float xu[8];
  {
    const float4 x0 = *(const float4*)(XU + (rowbase+r2)*KK + kq*8);
    const float4 x1 = *(const float4*)(XU + (rowbase+r2)*KK + kq*8 + 4);
    xu[0]=x0.x; xu[1]=x0.y; xu[2]=x0.z; xu[3]=x0.w;
    xu[4]=x1.x; xu[5]=x1.y; xu[6]=x1.z; xu[7]=x1.w;
  }
  const float gx = GX[rowbase + r2];
  float xp[8];
  #pragma unroll
  for (int i = 0; i < 8; ++i) xp[i] = fmaxf(xu[i], 0.f);
  float4 p[10];
  irow_compute(ypj, xp, kq, p);            // bitwise == I used for PmIn/PsIn
  // A = exp(I-M)*Si ; lane writes only its designated float4s of the e-tile
  #pragma unroll
  for (int m = 0; m < 10; ++m) {
    if ((m & 3) == kq) {
      float4 e4;
      e4.x = __expf(p[m].x - M_l[4*m+0]) * Si_l[4*m+0];
      e4.y = __expf(p[m].y - M_l[4*m+1]) * Si_l[4*m+1];
      e4.z = __expf(p[m].z - M_l[4*m+2]) * Si_l[4*m+2];
      e4.w = __expf(p[m].w - M_l[4*m+3]) * Si_l[4*m+3];
      *(float4*)(e_l + r2*44 + 4*m) = e4;
    }
  }
  __syncthreads();
  // phase B: h[n][k] = sum_j A[n][j]*yp[j][k]  (rows {rq, rq+32}, k = kc*4..+3)
  {
    const int rq = t >> 3, kc = t & 7;
    float4 h0 = make_float4(0.f,0.f,0.f,0.f), h1 = make_float4(0.f,0.f,0.f,0.f);
    #pragma unroll 4
    for (int j = 0; j < JJ; ++j) {
      const float4 yv = *(const float4*)(ypj + j*32 + kc*4);
      const float e0 = e_l[rq*44 + j];
      const float e1 = e_l[(rq+32)*44 + j];
      h0.x += e0*yv.x; h0.y += e0*yv.y; h0.z += e0*yv.z; h0.w += e0*yv.w;
      h1.x += e1*yv.x; h1.y += e1*yv.y; h1.z += e1*yv.z; h1.w += e1*yv.w;
    }
    h0.x = fmaxf(h0.x,0.f); h0.y = fmaxf(h0.y,0.f); h0.z = fmaxf(h0.z,0.f); h0.w = fmaxf(h0.w,0.f);
    h1.x = fmaxf(h1.x,0.f); h1.y = fmaxf(h1.y,0.f); h1.z = fmaxf(h1.z,0.f); h1.w = fmaxf(h1.w,0.f);
    *(float4*)(h_l + rq*40 + kc*4) = h0;
    *(float4*)(h_l + (rq+32)*40 + kc*4) = h1;
  }
  __syncthreads();
  // phase C: hu = h@VU, gate scalars, blend in K-space
  float hu[8] = {0,0,0,0,0,0,0,0};
  float gh2 = 0.f, ghx = 0.f;
  #pragma unroll 8
  for (int kp = 0; kp < KK; ++kp) {
    const float hv = h_l[r2*40 + kp];
    gh2 += hv * vghl[kp];
    ghx += hv * vgxl[kp];
    const float4 v0 = *(const float4*)(VUl + kp*32 + kq*8);
    const float4 v1 = *(const float4*)(VUl + kp*32 + kq*8 + 4);
    ACC8(hu, hv, v0, v1);
  }
  const float z = 1.f/(1.f + __expf(-(gx + gh2 + gb[0])));
  #pragma unroll
  for (int i = 0; i < 8; ++i) {
    xu[i] = (1.f - z)*xu[i] + z*hu[i];
    xp[i] = fmaxf(xu[i], 0.f);
  }
  if (!FINAL) {
    *(float4*)(XU + (rowbase+r2)*KK + kq*8)     = make_float4(xu[0],xu[1],xu[2],xu[3]);
    *(float4*)(XU + (rowbase+r2)*KK + kq*8 + 4) = make_float4(xu[4],xu[5],xu[6],xu[7]);
    if (kq == 0) GX[rowbase + r2] = (1.f - z)*gx + z*ghx;
  }
  // next-layer I
  irow_compute(ypj, xp, kq, p);
  if (FINAL) {
    float s = 0.f;
    #pragma unroll
    for (int m = 0; m < 10; ++m)
      s += p[m].x*p[m].x + p[m].y*p[m].y + p[m].z*p[m].z + p[m].w*p[m].w;
    if (kq == 0) outp[rowbase + r2] = 1.f/(1.f + __expf(-s));
    return;
  }
  partials_out(p, t, kq, sredm, sreds, redm,
               PmOut + (size_t)b*2560 + blk, PsOut + (size_t)b*2560 + blk);
}

extern "C" void kernel_launch(void* const* d_in, const int* in_sizes, int n_in,
                              void* d_out, int out_size, void* d_ws, size_t ws_size,
                              hipStream_t stream) {
  const float* nf  = (const float*)d_in[0];
  const float* fe  = (const float*)d_in[1];
  const float* W   = (const float*)d_in[2];
  const float* bin = (const float*)d_in[3];
  const float* U   = (const float*)d_in[4];
  const float* V   = (const float*)d_in[5];
  const float* q   = (const float*)d_in[6];
  const float* gw  = (const float*)d_in[7];
  const float* gb  = (const float*)d_in[8];
  float* out = (float*)d_out;
  float* wf  = (float*)d_ws;

  float* XU  = wf + XU_OFF;
  float* GX  = wf + GX_OFF;
  float* YP  = wf + YP_OFF;
  float* PMa = wf + PMA_OFF;
  float* PSa = wf + PSA_OFF;
  float* PMb = wf + PMB_OFF;
  float* PSb = wf + PSB_OFF;
  float* CWp = wf + CWS_OFF;
  double* ST = (double*)(wf + ST_OFF);

  hipMemsetAsync(ST, 0, 4*sizeof(double), stream);
  k_pre<<<1, 256, 0, stream>>>(W, bin, U, V, gw, CWp);
  k_stat<<<NTOT/64, 256, 0, stream>>>(nf, W, bin, ST);
  k_stat<<<YROWS/64, 256, 0, stream>>>(fe, W, bin, ST+2);
  k_yp2<<<YROWS/64, 256, 0, stream>>>(fe, CWp, q, ST, YP);
  k_I0<<<NTOT/64, 256, 0, stream>>>(nf, CWp, ST, YP, XU, GX, PMa, PSa);
  k_fused2<0><<<NTOT/64, 256, 0, stream>>>(XU, GX, YP, CWp, gb, PMa, PSa, PMb, PSb, nullptr);
  k_fused2<1><<<NTOT/64, 256, 0, stream>>>(XU, GX, YP, CWp, gb, PMb, PSb, nullptr, nullptr, out);
}